// Round 4
// baseline (1008.052 us; speedup 1.0000x reference)
//
#include <hip/hip_runtime.h>

// Problem constants (from reference)
constexpr int N_PART = 100000;
constexpr int N_EDGE = 6400000;
constexpr float SUPPORT = 0.05f;

// ===========================================================================
// Bucketed path: counting-sort edges by 256-particle bin, then one block per
// bin accumulates in LDS with zero global atomics (except O(200K) slot
// reservations in the sort).
// ===========================================================================
constexpr int BK_LOG2 = 8;
constexpr int BK      = 1 << BK_LOG2;                 // 256 particles per bin
constexpr int NBINS   = (N_PART + BK - 1) / BK;       // 391
constexpr int P_BUCKET = 512;                          // bucketize blocks
constexpr float PI_F = 3.14159265358979323846f;

__global__ __launch_bounds__(512) void init_counts(unsigned* __restrict__ gcount) {
    int k = threadIdx.x;
    if (k < NBINS + 1) gcount[k] = 0u;
}

// Histogram of destination particle i over bins (LDS hist, one flush per block)
__global__ __launch_bounds__(256) void hist_kernel(const int* __restrict__ nb,
                                                   unsigned* __restrict__ gcount) {
    __shared__ unsigned h[NBINS];
    for (int k = threadIdx.x; k < NBINS; k += blockDim.x) h[k] = 0u;
    __syncthreads();
    int gid = blockIdx.x * blockDim.x + threadIdx.x;
    int stride = gridDim.x * blockDim.x;
    for (int e = gid; e < N_EDGE; e += stride)
        atomicAdd(&h[nb[e] >> BK_LOG2], 1u);
    __syncthreads();
    for (int k = threadIdx.x; k < NBINS; k += blockDim.x) {
        unsigned c = h[k];
        if (c) atomicAdd(&gcount[k], c);
    }
}

// Exclusive prefix scan (391 values — serial on one thread is ~µs)
__global__ void scan_kernel(const unsigned* __restrict__ gcount,
                            unsigned* __restrict__ gbase,
                            unsigned* __restrict__ gcursor) {
    if (threadIdx.x == 0) {
        unsigned run = 0;
        for (int b = 0; b < NBINS; ++b) {
            gbase[b] = run;
            gcursor[b] = run;
            run += gcount[b];
        }
        gbase[NBINS] = run;   // == N_EDGE
    }
}

// Counting-sort scatter + payload precompute.
// pack = (i_local[8b] << 17) | j[17b]; pay1 = s*d (normals); pay2 = fc*kern*d.
__global__ __launch_bounds__(256) void bucketize_kernel(
    const int* __restrict__ nb,
    const float* __restrict__ areas,
    const float* __restrict__ dens,
    const float* __restrict__ rest,
    const float* __restrict__ q,
    const float2* __restrict__ dist,
    unsigned* __restrict__ gcursor,
    unsigned* __restrict__ gpack,
    float2* __restrict__ gpay1,
    float2* __restrict__ gpay2)
{
    __shared__ unsigned cnt[NBINS];
    __shared__ unsigned base[NBINS];

    const int blk   = blockIdx.x;
    const int start = (int)((long long)blk * N_EDGE / P_BUCKET);
    const int end   = (int)((long long)(blk + 1) * N_EDGE / P_BUCKET);

    for (int k = threadIdx.x; k < NBINS; k += blockDim.x) cnt[k] = 0u;
    __syncthreads();

    // Phase 1: per-block bin counts
    for (int e = start + (int)threadIdx.x; e < end; e += (int)blockDim.x)
        atomicAdd(&cnt[nb[e] >> BK_LOG2], 1u);
    __syncthreads();

    // Reserve global slots (one fabric atomic per (block,bin))
    for (int k = threadIdx.x; k < NBINS; k += blockDim.x) {
        unsigned c = cnt[k];
        base[k] = c ? atomicAdd(&gcursor[k], c) : 0u;
        cnt[k] = 0u;
    }
    __syncthreads();

    // Phase 2: compute payloads, scatter to reserved slots
    const float Cw = 7.0f / (PI_F * SUPPORT * SUPPORT);
    for (int e = start + (int)threadIdx.x; e < end; e += (int)blockDim.x) {
        int i = nb[e];
        int j = nb[N_EDGE + e];
        int bin = i >> BK_LOG2;
        unsigned slot = base[bin] + atomicAdd(&cnt[bin], 1u);

        float qq = q[e];
        float2 d = dist[e];

        // pass-1 payload: SUPPORT * (areas[j]/dens[j]) * dWdq(q)
        float omq  = fmaxf(1.0f - qq, 0.0f);
        float dWdq = Cw * (-20.0f * qq * omq * omq * omq) * (1.0f / SUPPORT);
        float s    = SUPPORT * (areas[j] / dens[j]) * dWdq;

        // cohesion payload: areas[j]*rest[j]*kern(q)   (net sign +, see R1)
        float qm1  = qq - 1.0f;
        float t    = qm1 * qm1 * qm1 * qq * qq * qq;
        float kern = (qq <= 0.5f) ? fmaf(128.0f, t, 1.0f) : 64.0f * t;
        float fc   = areas[j] * rest[j] * kern;

        gpack[slot] = ((unsigned)(i & (BK - 1)) << 17) | (unsigned)j;
        gpay1[slot] = make_float2(s * d.x, s * d.y);
        gpay2[slot] = make_float2(fc * d.x, fc * d.y);
    }
}

// Pass B: block b owns bin b. Accumulate normals + edge count in LDS; exact
// non-atomic writes.
__global__ __launch_bounds__(256) void passB_kernel(
    const unsigned* __restrict__ gbase,
    const unsigned* __restrict__ gpack,
    const float2* __restrict__ gpay1,
    float2* __restrict__ normals,        // [N]
    float* __restrict__ cntf)            // [N]
{
    __shared__ float ax[BK], ay[BK];
    __shared__ unsigned ac[BK];
    const int b = blockIdx.x;
    ax[threadIdx.x] = 0.0f; ay[threadIdx.x] = 0.0f; ac[threadIdx.x] = 0u;
    __syncthreads();

    const unsigned s0 = gbase[b], s1 = gbase[b + 1];
    for (unsigned k = s0 + threadIdx.x; k < s1; k += blockDim.x) {
        unsigned pk = gpack[k];
        float2 p = gpay1[k];
        unsigned loc = pk >> 17;
        atomicAdd(&ax[loc], p.x);
        atomicAdd(&ay[loc], p.y);
        atomicAdd(&ac[loc], 1u);
    }
    __syncthreads();

    int p = b * BK + (int)threadIdx.x;
    if (p < N_PART) {
        normals[p] = make_float2(ax[threadIdx.x], ay[threadIdx.x]);
        cntf[p]    = (float)ac[threadIdx.x];
    }
}

// Pass D: curvature + cohesion. Σ_e -(n_i - n_j) = -(cnt_i·n_i - Σ n_j).
__global__ __launch_bounds__(256) void passD_kernel(
    const unsigned* __restrict__ gbase,
    const unsigned* __restrict__ gpack,
    const float2* __restrict__ gpay2,
    const float2* __restrict__ normals,
    const float* __restrict__ cntf,
    float2* __restrict__ out)
{
    __shared__ float sx[BK], sy[BK], cx[BK], cy[BK];
    const int b = blockIdx.x;
    sx[threadIdx.x] = 0.0f; sy[threadIdx.x] = 0.0f;
    cx[threadIdx.x] = 0.0f; cy[threadIdx.x] = 0.0f;
    __syncthreads();

    const unsigned s0 = gbase[b], s1 = gbase[b + 1];
    for (unsigned k = s0 + threadIdx.x; k < s1; k += blockDim.x) {
        unsigned pk = gpack[k];
        float2 p2 = gpay2[k];
        unsigned j   = pk & 0x1FFFFu;
        unsigned loc = pk >> 17;
        float2 nj = normals[j];               // L2-resident 800 KB gather
        atomicAdd(&sx[loc], nj.x);
        atomicAdd(&sy[loc], nj.y);
        atomicAdd(&cx[loc], p2.x);
        atomicAdd(&cy[loc], p2.y);
    }
    __syncthreads();

    int p = b * BK + (int)threadIdx.x;
    if (p < N_PART) {
        float2 n = normals[p];
        float c  = cntf[p];
        out[p] = make_float2(-(c * n.x - sx[threadIdx.x]) + cx[threadIdx.x],
                             -(c * n.y - sy[threadIdx.x]) + cy[threadIdx.x]);
    }
}

// ===========================================================================
// Fallback 1 (R3): binned multi-read path (~4.4 MB ws). Fallback 2: atomics.
// ===========================================================================
constexpr int FB_BSZ_LOG2 = 13;
constexpr int FB_BSZ   = 1 << FB_BSZ_LOG2;
constexpr int FB_NBINS = (N_PART + FB_BSZ - 1) / FB_BSZ;
constexpr int FB_NP_PAD = FB_NBINS * FB_BSZ;
constexpr int FB_C_TARGET = 39;

__global__ __launch_bounds__(1024) void fb_pass1_binned(
    const int* __restrict__ nb, const float* __restrict__ areas,
    const float* __restrict__ dens, const float* __restrict__ q,
    const float2* __restrict__ dist, float* __restrict__ partials, int C)
{
    __shared__ float lds[2 * FB_BSZ];
    const int b = blockIdx.x % FB_NBINS;
    const int c = blockIdx.x / FB_NBINS;
    for (int k = threadIdx.x; k < 2 * FB_BSZ; k += blockDim.x) lds[k] = 0.0f;
    __syncthreads();
    const int start = (int)((long long)c       * (N_EDGE / 4) / C) * 4;
    const int end   = (int)((long long)(c + 1) * (N_EDGE / 4) / C) * 4;
    const int4* __restrict__ nb4 = (const int4*)nb;
    const float Cw = 7.0f / (PI_F * SUPPORT * SUPPORT);
    for (int e = start + (int)threadIdx.x * 4; e < end; e += (int)blockDim.x * 4) {
        int4 iq = nb4[e >> 2];
        #pragma unroll
        for (int k = 0; k < 4; ++k) {
            int iv = (k == 0) ? iq.x : (k == 1) ? iq.y : (k == 2) ? iq.z : iq.w;
            if ((iv >> FB_BSZ_LOG2) == b) {
                int ee = e + k;
                int j  = nb[N_EDGE + ee];
                float qq  = q[ee];
                float fac = areas[j] / dens[j];
                float omq  = fmaxf(1.0f - qq, 0.0f);
                float dWdq = Cw * (-20.0f * qq * omq * omq * omq) * (1.0f / SUPPORT);
                float s = SUPPORT * fac * dWdq;
                float2 d = dist[ee];
                int loc = (iv & (FB_BSZ - 1)) << 1;
                atomicAdd(&lds[loc],     s * d.x);
                atomicAdd(&lds[loc + 1], s * d.y);
            }
        }
    }
    __syncthreads();
    float2* __restrict__ dst = (float2*)partials + (size_t)c * FB_NP_PAD + (size_t)b * FB_BSZ;
    const float2* __restrict__ src = (const float2*)lds;
    for (int k = threadIdx.x; k < FB_BSZ; k += blockDim.x) dst[k] = src[k];
}

__global__ __launch_bounds__(1024) void fb_pass2_binned(
    const int* __restrict__ nb, const float* __restrict__ areas,
    const float* __restrict__ rest, const float* __restrict__ q,
    const float2* __restrict__ dist, const float2* __restrict__ normals,
    float* __restrict__ partials, int C)
{
    __shared__ float lds[2 * FB_BSZ];
    const int b = blockIdx.x % FB_NBINS;
    const int c = blockIdx.x / FB_NBINS;
    for (int k = threadIdx.x; k < 2 * FB_BSZ; k += blockDim.x) lds[k] = 0.0f;
    __syncthreads();
    const int start = (int)((long long)c       * (N_EDGE / 4) / C) * 4;
    const int end   = (int)((long long)(c + 1) * (N_EDGE / 4) / C) * 4;
    const int4* __restrict__ nb4 = (const int4*)nb;
    for (int e = start + (int)threadIdx.x * 4; e < end; e += (int)blockDim.x * 4) {
        int4 iq = nb4[e >> 2];
        #pragma unroll
        for (int k = 0; k < 4; ++k) {
            int iv = (k == 0) ? iq.x : (k == 1) ? iq.y : (k == 2) ? iq.z : iq.w;
            if ((iv >> FB_BSZ_LOG2) == b) {
                int ee = e + k;
                int j  = nb[N_EDGE + ee];
                float2 ni = normals[iv];
                float2 nj = normals[j];
                float qq  = q[ee];
                float fc  = areas[j] * rest[j];
                float qm1 = qq - 1.0f;
                float t   = qm1 * qm1 * qm1 * qq * qq * qq;
                float kern = (qq <= 0.5f) ? fmaf(128.0f, t, 1.0f) : 64.0f * t;
                float2 d = dist[ee];
                int loc = (iv & (FB_BSZ - 1)) << 1;
                atomicAdd(&lds[loc],     -(ni.x - nj.x) + fc * kern * d.x);
                atomicAdd(&lds[loc + 1], -(ni.y - nj.y) + fc * kern * d.y);
            }
        }
    }
    __syncthreads();
    float2* __restrict__ dst = (float2*)partials + (size_t)c * FB_NP_PAD + (size_t)b * FB_BSZ;
    const float2* __restrict__ src = (const float2*)lds;
    for (int k = threadIdx.x; k < FB_BSZ; k += blockDim.x) dst[k] = src[k];
}

__global__ __launch_bounds__(256) void fb_reduce_partials(
    const float* __restrict__ partials, float* __restrict__ dst, int C)
{
    int p = blockIdx.x * blockDim.x + threadIdx.x;
    if (p >= N_PART) return;
    const float2* __restrict__ p2 = (const float2*)partials;
    float ax = 0.0f, ay = 0.0f;
    for (int c = 0; c < C; ++c) {
        float2 v = p2[(size_t)c * FB_NP_PAD + p];
        ax += v.x; ay += v.y;
    }
    ((float2*)dst)[p] = make_float2(ax, ay);
}

__global__ __launch_bounds__(256) void fb_zero2(float* __restrict__ a,
                                                float* __restrict__ b, int n) {
    int idx = blockIdx.x * blockDim.x + threadIdx.x;
    if (idx < n) { a[idx] = 0.0f; b[idx] = 0.0f; }
}

__global__ __launch_bounds__(256) void fb_pass1_atomic(
    const int* __restrict__ nb, const float* __restrict__ areas,
    const float* __restrict__ dens, const float* __restrict__ q,
    const float2* __restrict__ dist, float* __restrict__ normals)
{
    int e = blockIdx.x * blockDim.x + threadIdx.x;
    if (e >= N_EDGE) return;
    int i = nb[e];
    int j = nb[N_EDGE + e];
    float qq  = q[e];
    float fac = areas[j] / dens[j];
    const float Cw = 7.0f / (PI_F * SUPPORT * SUPPORT);
    float omq  = fmaxf(1.0f - qq, 0.0f);
    float dWdq = Cw * (-20.0f * qq * omq * omq * omq) * (1.0f / SUPPORT);
    float s = SUPPORT * fac * dWdq;
    float2 d = dist[e];
    atomicAdd(&normals[2 * i],     s * d.x);
    atomicAdd(&normals[2 * i + 1], s * d.y);
}

__global__ __launch_bounds__(256) void fb_pass2_atomic(
    const int* __restrict__ nb, const float* __restrict__ areas,
    const float* __restrict__ rest, const float* __restrict__ q,
    const float2* __restrict__ dist, const float2* __restrict__ normals,
    float* __restrict__ out)
{
    int e = blockIdx.x * blockDim.x + threadIdx.x;
    if (e >= N_EDGE) return;
    int i = nb[e];
    int j = nb[N_EDGE + e];
    float2 ni = normals[i];
    float2 nj = normals[j];
    float qq  = q[e];
    float fc  = areas[j] * rest[j];
    float qm1 = qq - 1.0f;
    float t   = qm1 * qm1 * qm1 * qq * qq * qq;
    float kern = (qq <= 0.5f) ? fmaf(128.0f, t, 1.0f) : 64.0f * t;
    float2 d = dist[e];
    atomicAdd(&out[2 * i],     -(ni.x - nj.x) + fc * kern * d.x);
    atomicAdd(&out[2 * i + 1], -(ni.y - nj.y) + fc * kern * d.y);
}

// ===========================================================================
extern "C" void kernel_launch(void* const* d_in, const int* in_sizes, int n_in,
                              void* d_out, int out_size, void* d_ws, size_t ws_size,
                              hipStream_t stream) {
    const int*   nb    = (const int*)d_in[0];     // [2*E]
    const float* areas = (const float*)d_in[1];   // [N]
    const float* dens  = (const float*)d_in[2];   // [N]
    const float* rest  = (const float*)d_in[3];   // [N]
    const float* q     = (const float*)d_in[4];   // [E]
    const float* dist  = (const float*)d_in[5];   // [E,2]
    float* out = (float*)d_out;                   // [N,2]

    // --- Bucketed-path workspace layout ---
    size_t off = 0;
    auto take = [&](size_t bytes) { size_t o = off; off += (bytes + 255) & ~(size_t)255; return o; };
    size_t o_gcount  = take((NBINS + 1) * sizeof(unsigned));
    size_t o_gbase   = take((NBINS + 1) * sizeof(unsigned));
    size_t o_gcursor = take((NBINS + 1) * sizeof(unsigned));
    size_t o_normals = take((size_t)N_PART * sizeof(float2));
    size_t o_cntf    = take((size_t)N_PART * sizeof(float));
    size_t o_pack    = take((size_t)N_EDGE * sizeof(unsigned));
    size_t o_pay1    = take((size_t)N_EDGE * sizeof(float2));
    size_t o_pay2    = take((size_t)N_EDGE * sizeof(float2));
    const size_t need = off;

    char* ws = (char*)d_ws;

    if (ws_size >= need) {
        unsigned* gcount  = (unsigned*)(ws + o_gcount);
        unsigned* gbase   = (unsigned*)(ws + o_gbase);
        unsigned* gcursor = (unsigned*)(ws + o_gcursor);
        float2*   normals = (float2*)(ws + o_normals);
        float*    cntf    = (float*)(ws + o_cntf);
        unsigned* gpack   = (unsigned*)(ws + o_pack);
        float2*   gpay1   = (float2*)(ws + o_pay1);
        float2*   gpay2   = (float2*)(ws + o_pay2);

        init_counts<<<1, 512, 0, stream>>>(gcount);
        hist_kernel<<<256, 256, 0, stream>>>(nb, gcount);
        scan_kernel<<<1, 64, 0, stream>>>(gcount, gbase, gcursor);
        bucketize_kernel<<<P_BUCKET, 256, 0, stream>>>(
            nb, areas, dens, rest, q, (const float2*)dist,
            gcursor, gpack, gpay1, gpay2);
        passB_kernel<<<NBINS, BK, 0, stream>>>(gbase, gpack, gpay1, normals, cntf);
        passD_kernel<<<NBINS, BK, 0, stream>>>(gbase, gpack, gpay2, normals, cntf,
                                               (float2*)out);
        return;
    }

    // --- Fallback paths ---
    const size_t normals_pad = 1 << 20;
    float* normals  = (float*)d_ws;
    float* partials = (float*)((char*)d_ws + normals_pad);
    const size_t per_chunk = (size_t)FB_NP_PAD * 2 * sizeof(float);
    int C = 0;
    if (ws_size > normals_pad) {
        C = (int)((ws_size - normals_pad) / per_chunk);
        if (C > FB_C_TARGET) C = FB_C_TARGET;
    }

    if (C >= 4) {
        const int grid = FB_NBINS * C;
        fb_pass1_binned<<<grid, 1024, 0, stream>>>(
            nb, areas, dens, q, (const float2*)dist, partials, C);
        fb_reduce_partials<<<(N_PART + 255) / 256, 256, 0, stream>>>(partials, normals, C);
        fb_pass2_binned<<<grid, 1024, 0, stream>>>(
            nb, areas, rest, q, (const float2*)dist, (const float2*)normals, partials, C);
        fb_reduce_partials<<<(N_PART + 255) / 256, 256, 0, stream>>>(partials, out, C);
    } else {
        const int nv = 2 * N_PART;
        fb_zero2<<<(nv + 255) / 256, 256, 0, stream>>>(normals, out, nv);
        const int blocks = (N_EDGE + 255) / 256;
        fb_pass1_atomic<<<blocks, 256, 0, stream>>>(
            nb, areas, dens, q, (const float2*)dist, normals);
        fb_pass2_atomic<<<blocks, 256, 0, stream>>>(
            nb, areas, rest, q, (const float2*)dist, (const float2*)normals, out);
    }
}

// Round 6
// 532.289 us; speedup vs baseline: 1.8938x; 1.8938x over previous
//
#include <hip/hip_runtime.h>

// Problem constants (from reference)
constexpr int N_PART = 100000;
constexpr int N_EDGE = 6400000;
constexpr float SUPPORT = 0.05f;
constexpr float PI_F = 3.14159265358979323846f;

// ===========================================================================
// Sorted path: block-local counting sort (coalesced payload writes), then
// bin-owner LDS accumulation with zero global atomics.
// ===========================================================================
constexpr int CH_LOG2 = 13;
constexpr int CH      = 1 << CH_LOG2;            // 8192 edges per sort chunk
constexpr int NCH     = (N_EDGE + CH - 1) / CH;  // 782 chunks
constexpr int BIN_LOG2 = 13;
constexpr int BINSZ   = 1 << BIN_LOG2;           // 8192 particles per bin
constexpr int NBIN    = (N_PART + BINSZ - 1) / BINSZ;  // 13 bins
constexpr int G_MAX   = 39;                      // partial groups (13*39=507 blocks)

// --- Level 1: per-chunk counting sort by particle bin + payload precompute.
// Output (per chunk, contiguous, bin-grouped): pack = (i_loc13 << 17) | j17,
// pay1 = s*d (Wendland grad payload), pay2 = fc*kern*d (cohesion payload).
// btab[t*16+b] = local start of bin b's segment (u32); btab[t*16+13] = len.
__global__ __launch_bounds__(512) void l1_sort(
    const int* __restrict__ nb,        // [2*E]
    const float* __restrict__ areas,   // [N]
    const float* __restrict__ dens,    // [N]
    const float* __restrict__ rest,    // [N]
    const float* __restrict__ q,       // [E]
    const float2* __restrict__ dist,   // [E]
    unsigned* __restrict__ gpack,
    float2* __restrict__ gpay1,
    float2* __restrict__ gpay2,
    unsigned* __restrict__ btab)       // [NCH*16] u32
{
    __shared__ unsigned perm[CH];            // 32 KB: sorted pos -> local edge id
    __shared__ unsigned hist[8 * NBIN];      // per-wave histogram replicas
    __shared__ unsigned base[NBIN + 1];
    __shared__ unsigned cur[NBIN];

    const int t   = blockIdx.x;
    const int c0  = t * CH;
    const int len = min(CH, N_EDGE - c0);
    const int tid = threadIdx.x;
    const int wid = tid >> 6;                // 8 waves

    for (int k = tid; k < 8 * NBIN; k += 512) hist[k] = 0u;
    __syncthreads();

    // Phase 1: coalesced read of i, per-wave histogram
    for (int idx = tid; idx < len; idx += 512) {
        unsigned i = (unsigned)nb[c0 + idx];
        atomicAdd(&hist[wid * NBIN + (i >> BIN_LOG2)], 1u);
    }
    __syncthreads();

    // Serial scan over 13 bins
    if (tid == 0) {
        unsigned run = 0;
        for (int b = 0; b < NBIN; ++b) {
            unsigned c = 0;
            for (int w = 0; w < 8; ++w) c += hist[w * NBIN + b];
            base[b] = run;
            cur[b]  = run;
            run += c;
        }
        base[NBIN] = run;   // == len
    }
    __syncthreads();
    if (tid < NBIN)  btab[t * 16 + tid]  = base[tid];
    if (tid == NBIN) btab[t * 16 + NBIN] = (unsigned)len;

    // Phase 2: rank within bin (re-read of i hits L1/L2-hot 32 KB window)
    for (int idx = tid; idx < len; idx += 512) {
        unsigned i = (unsigned)nb[c0 + idx];
        unsigned r = atomicAdd(&cur[i >> BIN_LOG2], 1u);
        perm[r] = (unsigned)idx;
    }
    __syncthreads();

    // Phase 3: walk output positions in order (coalesced stores); gather
    // i/j/q/dist through the cache-hot chunk windows; compute payloads.
    const float Cw = 7.0f / (PI_F * SUPPORT * SUPPORT);
    for (int p = tid; p < len; p += 512) {
        int eloc = (int)perm[p];
        int e = c0 + eloc;
        unsigned i = (unsigned)nb[e];
        unsigned j = (unsigned)nb[N_EDGE + e];
        float qq = q[e];
        float2 d = dist[e];

        // pass-1 payload: SUPPORT * (areas[j]/dens[j]) * dWdq(q)
        float omq  = fmaxf(1.0f - qq, 0.0f);
        float dWdq = Cw * (-20.0f * qq * omq * omq * omq) * (1.0f / SUPPORT);
        float s    = SUPPORT * (areas[j] / dens[j]) * dWdq;

        // cohesion payload: areas[j]*rest[j]*kern(q)  (net sign +, see R1)
        float qm1  = qq - 1.0f;
        float tt   = qm1 * qm1 * qm1 * qq * qq * qq;
        float kern = (qq <= 0.5f) ? fmaf(128.0f, tt, 1.0f) : 64.0f * tt;
        float fc   = areas[j] * rest[j] * kern;

        int o = c0 + p;
        gpack[o] = ((i & (BINSZ - 1)) << 17) | j;
        gpay1[o] = make_float2(s * d.x, s * d.y);
        gpay2[o] = make_float2(fc * d.x, fc * d.y);
    }
}

// --- Pass B: accumulate normals per bin from sorted segments --------------
__global__ __launch_bounds__(512) void passB(
    const unsigned* __restrict__ btab,
    const unsigned* __restrict__ gpack,
    const float2* __restrict__ gpay1,
    float2* __restrict__ partials,       // [G][NBIN*BINSZ]
    int G)
{
    __shared__ float acc[2 * BINSZ];     // 64 KB
    const int b = blockIdx.x % NBIN;
    const int g = blockIdx.x / NBIN;

    for (int k = threadIdx.x; k < 2 * BINSZ; k += 512) acc[k] = 0.0f;
    __syncthreads();

    const int t0 = (int)((long long)g * NCH / G);
    const int t1 = (int)((long long)(g + 1) * NCH / G);
    for (int t = t0; t < t1; ++t) {
        const int c0  = t * CH;
        const unsigned ln = min(btab[t * 16 + NBIN], (unsigned)CH);
        unsigned sb = min(btab[t * 16 + b], ln);
        unsigned se = min(btab[t * 16 + b + 1], ln);
        for (unsigned k = sb + threadIdx.x; k < se; k += 512) {
            int o = c0 + (int)k;
            unsigned pk = gpack[o];
            float2 p = gpay1[o];
            unsigned loc = (pk >> 17) & (BINSZ - 1);   // 13-bit mask: LDS-safe
            atomicAdd(&acc[2 * loc],     p.x);
            atomicAdd(&acc[2 * loc + 1], p.y);
        }
    }
    __syncthreads();

    float2* __restrict__ dst = partials + (size_t)g * (NBIN * BINSZ) + (size_t)b * BINSZ;
    const float2* __restrict__ src = (const float2*)acc;
    for (int k = threadIdx.x; k < BINSZ; k += 512) dst[k] = src[k];
}

// --- Pass D: acc_i += (n_j - n_i + coh) per edge --------------------------
__global__ __launch_bounds__(512) void passD(
    const unsigned* __restrict__ btab,
    const unsigned* __restrict__ gpack,
    const float2* __restrict__ gpay2,
    const float2* __restrict__ normals,  // [N]
    float2* __restrict__ partials,
    int G)
{
    __shared__ float acc[2 * BINSZ];
    const int b = blockIdx.x % NBIN;
    const int g = blockIdx.x / NBIN;

    for (int k = threadIdx.x; k < 2 * BINSZ; k += 512) acc[k] = 0.0f;
    __syncthreads();

    const int gbase = b * BINSZ;
    const int t0 = (int)((long long)g * NCH / G);
    const int t1 = (int)((long long)(g + 1) * NCH / G);
    for (int t = t0; t < t1; ++t) {
        const int c0  = t * CH;
        const unsigned ln = min(btab[t * 16 + NBIN], (unsigned)CH);
        unsigned sb = min(btab[t * 16 + b], ln);
        unsigned se = min(btab[t * 16 + b + 1], ln);
        for (unsigned k = sb + threadIdx.x; k < se; k += 512) {
            int o = c0 + (int)k;
            unsigned pk = gpack[o];
            float2 coh = gpay2[o];
            unsigned loc = (pk >> 17) & (BINSZ - 1);            // LDS-safe
            unsigned j   = min(pk & 0x1FFFFu, (unsigned)(N_PART - 1));
            unsigned ii  = min((unsigned)(gbase + loc), (unsigned)(N_PART - 1));
            float2 nj = normals[j];            // random, L2-resident 800 KB
            float2 ni = normals[ii];           // hot 64 KB window
            atomicAdd(&acc[2 * loc],     nj.x - ni.x + coh.x);
            atomicAdd(&acc[2 * loc + 1], nj.y - ni.y + coh.y);
        }
    }
    __syncthreads();

    float2* __restrict__ dst = partials + (size_t)g * (NBIN * BINSZ) + (size_t)b * BINSZ;
    const float2* __restrict__ src = (const float2*)acc;
    for (int k = threadIdx.x; k < BINSZ; k += 512) dst[k] = src[k];
}

// dst[p] = sum_g partials[g][p]
__global__ __launch_bounds__(256) void reduceG(
    const float2* __restrict__ partials, float2* __restrict__ dst, int G)
{
    int p = blockIdx.x * blockDim.x + threadIdx.x;
    if (p >= N_PART) return;
    float ax = 0.0f, ay = 0.0f;
    for (int g = 0; g < G; ++g) {
        float2 v = partials[(size_t)g * (NBIN * BINSZ) + p];
        ax += v.x; ay += v.y;
    }
    dst[p] = make_float2(ax, ay);
}

// ===========================================================================
// Fallback 1 (R3, proven 631 us): binned multi-read path. Fallback 2: atomics.
// ===========================================================================
constexpr int FB_BSZ_LOG2 = 13;
constexpr int FB_BSZ   = 1 << FB_BSZ_LOG2;
constexpr int FB_NBINS = (N_PART + FB_BSZ - 1) / FB_BSZ;
constexpr int FB_NP_PAD = FB_NBINS * FB_BSZ;
constexpr int FB_C_TARGET = 39;

__global__ __launch_bounds__(1024) void fb_pass1_binned(
    const int* __restrict__ nb, const float* __restrict__ areas,
    const float* __restrict__ dens, const float* __restrict__ q,
    const float2* __restrict__ dist, float* __restrict__ partials, int C)
{
    __shared__ float lds[2 * FB_BSZ];
    const int b = blockIdx.x % FB_NBINS;
    const int c = blockIdx.x / FB_NBINS;
    for (int k = threadIdx.x; k < 2 * FB_BSZ; k += blockDim.x) lds[k] = 0.0f;
    __syncthreads();
    const int start = (int)((long long)c       * (N_EDGE / 4) / C) * 4;
    const int end   = (int)((long long)(c + 1) * (N_EDGE / 4) / C) * 4;
    const int4* __restrict__ nb4 = (const int4*)nb;
    const float Cw = 7.0f / (PI_F * SUPPORT * SUPPORT);
    for (int e = start + (int)threadIdx.x * 4; e < end; e += (int)blockDim.x * 4) {
        int4 iq = nb4[e >> 2];
        #pragma unroll
        for (int k = 0; k < 4; ++k) {
            int iv = (k == 0) ? iq.x : (k == 1) ? iq.y : (k == 2) ? iq.z : iq.w;
            if ((iv >> FB_BSZ_LOG2) == b) {
                int ee = e + k;
                int j  = nb[N_EDGE + ee];
                float qq  = q[ee];
                float fac = areas[j] / dens[j];
                float omq  = fmaxf(1.0f - qq, 0.0f);
                float dWdq = Cw * (-20.0f * qq * omq * omq * omq) * (1.0f / SUPPORT);
                float s = SUPPORT * fac * dWdq;
                float2 d = dist[ee];
                int loc = (iv & (FB_BSZ - 1)) << 1;
                atomicAdd(&lds[loc],     s * d.x);
                atomicAdd(&lds[loc + 1], s * d.y);
            }
        }
    }
    __syncthreads();
    float2* __restrict__ dst = (float2*)partials + (size_t)c * FB_NP_PAD + (size_t)b * FB_BSZ;
    const float2* __restrict__ src = (const float2*)lds;
    for (int k = threadIdx.x; k < FB_BSZ; k += blockDim.x) dst[k] = src[k];
}

__global__ __launch_bounds__(1024) void fb_pass2_binned(
    const int* __restrict__ nb, const float* __restrict__ areas,
    const float* __restrict__ rest, const float* __restrict__ q,
    const float2* __restrict__ dist, const float2* __restrict__ normals,
    float* __restrict__ partials, int C)
{
    __shared__ float lds[2 * FB_BSZ];
    const int b = blockIdx.x % FB_NBINS;
    const int c = blockIdx.x / FB_NBINS;
    for (int k = threadIdx.x; k < 2 * FB_BSZ; k += blockDim.x) lds[k] = 0.0f;
    __syncthreads();
    const int start = (int)((long long)c       * (N_EDGE / 4) / C) * 4;
    const int end   = (int)((long long)(c + 1) * (N_EDGE / 4) / C) * 4;
    const int4* __restrict__ nb4 = (const int4*)nb;
    for (int e = start + (int)threadIdx.x * 4; e < end; e += (int)blockDim.x * 4) {
        int4 iq = nb4[e >> 2];
        #pragma unroll
        for (int k = 0; k < 4; ++k) {
            int iv = (k == 0) ? iq.x : (k == 1) ? iq.y : (k == 2) ? iq.z : iq.w;
            if ((iv >> FB_BSZ_LOG2) == b) {
                int ee = e + k;
                int j  = nb[N_EDGE + ee];
                float2 ni = normals[iv];
                float2 nj = normals[j];
                float qq  = q[ee];
                float fc  = areas[j] * rest[j];
                float qm1 = qq - 1.0f;
                float t   = qm1 * qm1 * qm1 * qq * qq * qq;
                float kern = (qq <= 0.5f) ? fmaf(128.0f, t, 1.0f) : 64.0f * t;
                float2 d = dist[ee];
                int loc = (iv & (FB_BSZ - 1)) << 1;
                atomicAdd(&lds[loc],     -(ni.x - nj.x) + fc * kern * d.x);
                atomicAdd(&lds[loc + 1], -(ni.y - nj.y) + fc * kern * d.y);
            }
        }
    }
    __syncthreads();
    float2* __restrict__ dst = (float2*)partials + (size_t)c * FB_NP_PAD + (size_t)b * FB_BSZ;
    const float2* __restrict__ src = (const float2*)lds;
    for (int k = threadIdx.x; k < FB_BSZ; k += blockDim.x) dst[k] = src[k];
}

__global__ __launch_bounds__(256) void fb_reduce_partials(
    const float* __restrict__ partials, float* __restrict__ dst, int C)
{
    int p = blockIdx.x * blockDim.x + threadIdx.x;
    if (p >= N_PART) return;
    const float2* __restrict__ p2 = (const float2*)partials;
    float ax = 0.0f, ay = 0.0f;
    for (int c = 0; c < C; ++c) {
        float2 v = p2[(size_t)c * FB_NP_PAD + p];
        ax += v.x; ay += v.y;
    }
    ((float2*)dst)[p] = make_float2(ax, ay);
}

__global__ __launch_bounds__(256) void fb_zero2(float* __restrict__ a,
                                                float* __restrict__ b, int n) {
    int idx = blockIdx.x * blockDim.x + threadIdx.x;
    if (idx < n) { a[idx] = 0.0f; b[idx] = 0.0f; }
}

__global__ __launch_bounds__(256) void fb_pass1_atomic(
    const int* __restrict__ nb, const float* __restrict__ areas,
    const float* __restrict__ dens, const float* __restrict__ q,
    const float2* __restrict__ dist, float* __restrict__ normals)
{
    int e = blockIdx.x * blockDim.x + threadIdx.x;
    if (e >= N_EDGE) return;
    int i = nb[e];
    int j = nb[N_EDGE + e];
    float qq  = q[e];
    float fac = areas[j] / dens[j];
    const float Cw = 7.0f / (PI_F * SUPPORT * SUPPORT);
    float omq  = fmaxf(1.0f - qq, 0.0f);
    float dWdq = Cw * (-20.0f * qq * omq * omq * omq) * (1.0f / SUPPORT);
    float s = SUPPORT * fac * dWdq;
    float2 d = dist[e];
    atomicAdd(&normals[2 * i],     s * d.x);
    atomicAdd(&normals[2 * i + 1], s * d.y);
}

__global__ __launch_bounds__(256) void fb_pass2_atomic(
    const int* __restrict__ nb, const float* __restrict__ areas,
    const float* __restrict__ rest, const float* __restrict__ q,
    const float2* __restrict__ dist, const float2* __restrict__ normals,
    float* __restrict__ out)
{
    int e = blockIdx.x * blockDim.x + threadIdx.x;
    if (e >= N_EDGE) return;
    int i = nb[e];
    int j = nb[N_EDGE + e];
    float2 ni = normals[i];
    float2 nj = normals[j];
    float qq  = q[e];
    float fc  = areas[j] * rest[j];
    float qm1 = qq - 1.0f;
    float t   = qm1 * qm1 * qm1 * qq * qq * qq;
    float kern = (qq <= 0.5f) ? fmaf(128.0f, t, 1.0f) : 64.0f * t;
    float2 d = dist[e];
    atomicAdd(&out[2 * i],     -(ni.x - nj.x) + fc * kern * d.x);
    atomicAdd(&out[2 * i + 1], -(ni.y - nj.y) + fc * kern * d.y);
}

// ===========================================================================
extern "C" void kernel_launch(void* const* d_in, const int* in_sizes, int n_in,
                              void* d_out, int out_size, void* d_ws, size_t ws_size,
                              hipStream_t stream) {
    const int*   nb    = (const int*)d_in[0];     // [2*E]
    const float* areas = (const float*)d_in[1];   // [N]
    const float* dens  = (const float*)d_in[2];   // [N]
    const float* rest  = (const float*)d_in[3];   // [N]
    const float* q     = (const float*)d_in[4];   // [E]
    const float* dist  = (const float*)d_in[5];   // [E,2]
    float* out = (float*)d_out;                   // [N,2]

    // --- Sorted-path workspace layout ---
    size_t off = 0;
    auto take = [&](size_t bytes) { size_t o = off; off += (bytes + 255) & ~(size_t)255; return o; };
    size_t o_pack    = take((size_t)N_EDGE * sizeof(unsigned));
    size_t o_pay1    = take((size_t)N_EDGE * sizeof(float2));
    size_t o_pay2    = take((size_t)N_EDGE * sizeof(float2));
    size_t o_btab    = take((size_t)NCH * 16 * sizeof(unsigned));
    size_t o_normals = take((size_t)N_PART * sizeof(float2));
    size_t base_need = off;
    const size_t per_g = (size_t)(NBIN * BINSZ) * sizeof(float2);

    int G = 0;
    if (ws_size > base_need) {
        G = (int)((ws_size - base_need) / per_g);
        if (G > G_MAX) G = G_MAX;
    }

    char* ws = (char*)d_ws;

    if (G >= 6) {
        unsigned* gpack   = (unsigned*)(ws + o_pack);
        float2*   gpay1   = (float2*)(ws + o_pay1);
        float2*   gpay2   = (float2*)(ws + o_pay2);
        unsigned* btab    = (unsigned*)(ws + o_btab);
        float2*   normals = (float2*)(ws + o_normals);
        float2*   partials= (float2*)(ws + base_need);

        l1_sort<<<NCH, 512, 0, stream>>>(
            nb, areas, dens, rest, q, (const float2*)dist,
            gpack, gpay1, gpay2, btab);
        passB<<<NBIN * G, 512, 0, stream>>>(btab, gpack, gpay1, partials, G);
        reduceG<<<(N_PART + 255) / 256, 256, 0, stream>>>(partials, normals, G);
        passD<<<NBIN * G, 512, 0, stream>>>(btab, gpack, gpay2, normals, partials, G);
        reduceG<<<(N_PART + 255) / 256, 256, 0, stream>>>(partials, (float2*)out, G);
        return;
    }

    // --- Fallback paths ---
    const size_t normals_pad = 1 << 20;
    float* normals  = (float*)d_ws;
    float* partials = (float*)((char*)d_ws + normals_pad);
    const size_t per_chunk = (size_t)FB_NP_PAD * 2 * sizeof(float);
    int C = 0;
    if (ws_size > normals_pad) {
        C = (int)((ws_size - normals_pad) / per_chunk);
        if (C > FB_C_TARGET) C = FB_C_TARGET;
    }

    if (C >= 4) {
        const int grid = FB_NBINS * C;
        fb_pass1_binned<<<grid, 1024, 0, stream>>>(
            nb, areas, dens, q, (const float2*)dist, partials, C);
        fb_reduce_partials<<<(N_PART + 255) / 256, 256, 0, stream>>>(partials, normals, C);
        fb_pass2_binned<<<grid, 1024, 0, stream>>>(
            nb, areas, rest, q, (const float2*)dist, (const float2*)normals, partials, C);
        fb_reduce_partials<<<(N_PART + 255) / 256, 256, 0, stream>>>(partials, out, C);
    } else {
        const int nv = 2 * N_PART;
        fb_zero2<<<(nv + 255) / 256, 256, 0, stream>>>(normals, out, nv);
        const int blocks = (N_EDGE + 255) / 256;
        fb_pass1_atomic<<<blocks, 256, 0, stream>>>(
            nb, areas, dens, q, (const float2*)dist, normals);
        fb_pass2_atomic<<<blocks, 256, 0, stream>>>(
            nb, areas, rest, q, (const float2*)dist, (const float2*)normals, out);
    }
}

// Round 7
// 450.927 us; speedup vs baseline: 2.2355x; 1.1804x over previous
//
#include <hip/hip_runtime.h>

// Problem constants (from reference)
constexpr int N_PART = 100000;
constexpr int N_EDGE = 6400000;
constexpr float SUPPORT = 0.05f;
constexpr float PI_F = 3.14159265358979323846f;

// ===========================================================================
// Sorted path: block-local counting sort (records staged in LDS, all global
// traffic coalesced), then bin-owner LDS accumulation, zero global atomics.
// ===========================================================================
constexpr int CH_LOG2 = 13;
constexpr int CH      = 1 << CH_LOG2;            // 8192 edges per sort chunk
constexpr int NCH     = (N_EDGE + CH - 1) / CH;  // 782 chunks
constexpr int BIN_LOG2 = 13;
constexpr int BINSZ   = 1 << BIN_LOG2;           // 8192 particles per bin
constexpr int NBIN    = (N_PART + BINSZ - 1) / BINSZ;  // 13 bins
constexpr int G_MAX   = 39;                      // partial groups (13*39=507 blocks)
constexpr int ST_NW   = 16;                      // l1_sort waves (1024 threads)

// --- Level 1: per-chunk counting sort + payload precompute.
// All global reads/writes coalesced; the permutation happens inside LDS.
// Output (per chunk, bin-grouped): pack = (i_loc13 << 17) | j17,
// pay1 = s*d (Wendland grad payload), pay2 = fc*kern*d (cohesion payload).
// btab[t*16+b] = local start of bin b's segment; btab[t*16+13] = chunk len.
__global__ __launch_bounds__(1024) void l1_sort(
    const int* __restrict__ nb,        // [2*E]
    const float* __restrict__ areas,   // [N]
    const float* __restrict__ dens,    // [N]
    const float* __restrict__ rest,    // [N]
    const float* __restrict__ q,       // [E]
    const float2* __restrict__ dist,   // [E]
    unsigned* __restrict__ gpack,
    float2* __restrict__ gpay1,
    float2* __restrict__ gpay2,
    unsigned* __restrict__ btab)       // [NCH*16] u32
{
    __shared__ float4  rec[CH];               // 128 KB: {pack,q,dx,dy} sorted
    __shared__ unsigned hist[ST_NW * NBIN];   // per-wave histograms
    __shared__ unsigned curw[ST_NW * NBIN];   // per-(wave,bin) write cursors
    __shared__ unsigned base[NBIN + 1];

    const int t   = blockIdx.x;
    const int c0  = t * CH;
    const int len = min(CH, N_EDGE - c0);
    const int tid = threadIdx.x;
    const int wid = tid >> 6;                 // 16 waves

    for (int k = tid; k < ST_NW * NBIN; k += 1024) hist[k] = 0u;
    __syncthreads();

    // Phase 1: coalesced read of i, per-wave histogram (intra-wave atomics)
    for (int idx = tid; idx < len; idx += 1024) {
        unsigned i = (unsigned)nb[c0 + idx];
        atomicAdd(&hist[wid * NBIN + (i >> BIN_LOG2)], 1u);
    }
    __syncthreads();

    // Serial scan: bin bases + per-(wave,bin) cursors (13*16 = 208 iters)
    if (tid == 0) {
        unsigned run = 0;
        for (int b = 0; b < NBIN; ++b) {
            base[b] = run;
            for (int w = 0; w < ST_NW; ++w) {
                curw[w * NBIN + b] = run;
                run += hist[w * NBIN + b];
            }
        }
        base[NBIN] = run;   // == len
    }
    __syncthreads();
    if (tid < NBIN)  btab[t * 16 + tid]  = base[tid];
    if (tid == NBIN) btab[t * 16 + NBIN] = (unsigned)len;

    // Phase 2: coalesced read of all edge data; rank via own wave's cursor
    // (no cross-wave contention); scatter 16B record into LDS.
    for (int idx = tid; idx < len; idx += 1024) {
        unsigned i = (unsigned)nb[c0 + idx];
        unsigned j = (unsigned)nb[N_EDGE + c0 + idx];
        float   qq = q[c0 + idx];
        float2  d  = dist[c0 + idx];
        unsigned bin = i >> BIN_LOG2;
        unsigned r = atomicAdd(&curw[wid * NBIN + bin], 1u) & (CH - 1);
        unsigned pack = ((i & (BINSZ - 1)) << 17) | j;
        rec[r] = make_float4(__uint_as_float(pack), qq, d.x, d.y);
    }
    __syncthreads();

    // Phase 3: walk sorted positions (LDS read coalesced); gather only the
    // shared L2-resident areas/dens/rest; write everything coalesced.
    const float Cw = 7.0f / (PI_F * SUPPORT * SUPPORT);
    for (int p = tid; p < len; p += 1024) {
        float4 rc = rec[p];
        unsigned pack = __float_as_uint(rc.x);
        unsigned j = pack & 0x1FFFFu;
        float qq = rc.y;
        float dx = rc.z, dy = rc.w;

        // pass-1 payload: SUPPORT * (areas[j]/dens[j]) * dWdq(q)
        float omq  = fmaxf(1.0f - qq, 0.0f);
        float dWdq = Cw * (-20.0f * qq * omq * omq * omq) * (1.0f / SUPPORT);
        float s    = SUPPORT * (areas[j] / dens[j]) * dWdq;

        // cohesion payload: areas[j]*rest[j]*kern(q)  (net sign +, see R1)
        float qm1  = qq - 1.0f;
        float tt   = qm1 * qm1 * qm1 * qq * qq * qq;
        float kern = (qq <= 0.5f) ? fmaf(128.0f, tt, 1.0f) : 64.0f * tt;
        float fc   = areas[j] * rest[j] * kern;

        int o = c0 + p;
        gpack[o] = pack;
        gpay1[o] = make_float2(s * dx, s * dy);
        gpay2[o] = make_float2(fc * dx, fc * dy);
    }
}

// --- Pass B: accumulate normals per bin from sorted segments --------------
__global__ __launch_bounds__(512) void passB(
    const unsigned* __restrict__ btab,
    const unsigned* __restrict__ gpack,
    const float2* __restrict__ gpay1,
    float2* __restrict__ partials,       // [G][NBIN*BINSZ]
    int G)
{
    __shared__ float acc[2 * BINSZ];     // 64 KB
    const int b = blockIdx.x % NBIN;
    const int g = blockIdx.x / NBIN;

    for (int k = threadIdx.x; k < 2 * BINSZ; k += 512) acc[k] = 0.0f;
    __syncthreads();

    const int t0 = (int)((long long)g * NCH / G);
    const int t1 = (int)((long long)(g + 1) * NCH / G);
    for (int t = t0; t < t1; ++t) {
        const int c0  = t * CH;
        const unsigned ln = min(btab[t * 16 + NBIN], (unsigned)CH);
        unsigned sb = min(btab[t * 16 + b], ln);
        unsigned se = min(btab[t * 16 + b + 1], ln);
        for (unsigned k = sb + threadIdx.x; k < se; k += 512) {
            int o = c0 + (int)k;
            unsigned pk = gpack[o];
            float2 p = gpay1[o];
            unsigned loc = (pk >> 17) & (BINSZ - 1);   // 13-bit mask: LDS-safe
            atomicAdd(&acc[2 * loc],     p.x);
            atomicAdd(&acc[2 * loc + 1], p.y);
        }
    }
    __syncthreads();

    float2* __restrict__ dst = partials + (size_t)g * (NBIN * BINSZ) + (size_t)b * BINSZ;
    const float2* __restrict__ src = (const float2*)acc;
    for (int k = threadIdx.x; k < BINSZ; k += 512) dst[k] = src[k];
}

// --- Pass D: acc_i += (n_j - n_i + coh) per edge --------------------------
__global__ __launch_bounds__(512) void passD(
    const unsigned* __restrict__ btab,
    const unsigned* __restrict__ gpack,
    const float2* __restrict__ gpay2,
    const float2* __restrict__ normals,  // [N]
    float2* __restrict__ partials,
    int G)
{
    __shared__ float acc[2 * BINSZ];
    const int b = blockIdx.x % NBIN;
    const int g = blockIdx.x / NBIN;

    for (int k = threadIdx.x; k < 2 * BINSZ; k += 512) acc[k] = 0.0f;
    __syncthreads();

    const int gbase = b * BINSZ;
    const int t0 = (int)((long long)g * NCH / G);
    const int t1 = (int)((long long)(g + 1) * NCH / G);
    for (int t = t0; t < t1; ++t) {
        const int c0  = t * CH;
        const unsigned ln = min(btab[t * 16 + NBIN], (unsigned)CH);
        unsigned sb = min(btab[t * 16 + b], ln);
        unsigned se = min(btab[t * 16 + b + 1], ln);
        for (unsigned k = sb + threadIdx.x; k < se; k += 512) {
            int o = c0 + (int)k;
            unsigned pk = gpack[o];
            float2 coh = gpay2[o];
            unsigned loc = (pk >> 17) & (BINSZ - 1);            // LDS-safe
            unsigned j   = min(pk & 0x1FFFFu, (unsigned)(N_PART - 1));
            unsigned ii  = min((unsigned)(gbase + loc), (unsigned)(N_PART - 1));
            float2 nj = normals[j];            // random, L2-resident 800 KB
            float2 ni = normals[ii];           // hot 64 KB window
            atomicAdd(&acc[2 * loc],     nj.x - ni.x + coh.x);
            atomicAdd(&acc[2 * loc + 1], nj.y - ni.y + coh.y);
        }
    }
    __syncthreads();

    float2* __restrict__ dst = partials + (size_t)g * (NBIN * BINSZ) + (size_t)b * BINSZ;
    const float2* __restrict__ src = (const float2*)acc;
    for (int k = threadIdx.x; k < BINSZ; k += 512) dst[k] = src[k];
}

// dst[p] = sum_g partials[g][p]
__global__ __launch_bounds__(256) void reduceG(
    const float2* __restrict__ partials, float2* __restrict__ dst, int G)
{
    int p = blockIdx.x * blockDim.x + threadIdx.x;
    if (p >= N_PART) return;
    float ax = 0.0f, ay = 0.0f;
    for (int g = 0; g < G; ++g) {
        float2 v = partials[(size_t)g * (NBIN * BINSZ) + p];
        ax += v.x; ay += v.y;
    }
    dst[p] = make_float2(ax, ay);
}

// ===========================================================================
// Fallback 1 (R3, proven 631 us): binned multi-read path. Fallback 2: atomics.
// ===========================================================================
constexpr int FB_BSZ_LOG2 = 13;
constexpr int FB_BSZ   = 1 << FB_BSZ_LOG2;
constexpr int FB_NBINS = (N_PART + FB_BSZ - 1) / FB_BSZ;
constexpr int FB_NP_PAD = FB_NBINS * FB_BSZ;
constexpr int FB_C_TARGET = 39;

__global__ __launch_bounds__(1024) void fb_pass1_binned(
    const int* __restrict__ nb, const float* __restrict__ areas,
    const float* __restrict__ dens, const float* __restrict__ q,
    const float2* __restrict__ dist, float* __restrict__ partials, int C)
{
    __shared__ float lds[2 * FB_BSZ];
    const int b = blockIdx.x % FB_NBINS;
    const int c = blockIdx.x / FB_NBINS;
    for (int k = threadIdx.x; k < 2 * FB_BSZ; k += blockDim.x) lds[k] = 0.0f;
    __syncthreads();
    const int start = (int)((long long)c       * (N_EDGE / 4) / C) * 4;
    const int end   = (int)((long long)(c + 1) * (N_EDGE / 4) / C) * 4;
    const int4* __restrict__ nb4 = (const int4*)nb;
    const float Cw = 7.0f / (PI_F * SUPPORT * SUPPORT);
    for (int e = start + (int)threadIdx.x * 4; e < end; e += (int)blockDim.x * 4) {
        int4 iq = nb4[e >> 2];
        #pragma unroll
        for (int k = 0; k < 4; ++k) {
            int iv = (k == 0) ? iq.x : (k == 1) ? iq.y : (k == 2) ? iq.z : iq.w;
            if ((iv >> FB_BSZ_LOG2) == b) {
                int ee = e + k;
                int j  = nb[N_EDGE + ee];
                float qq  = q[ee];
                float fac = areas[j] / dens[j];
                float omq  = fmaxf(1.0f - qq, 0.0f);
                float dWdq = Cw * (-20.0f * qq * omq * omq * omq) * (1.0f / SUPPORT);
                float s = SUPPORT * fac * dWdq;
                float2 d = dist[ee];
                int loc = (iv & (FB_BSZ - 1)) << 1;
                atomicAdd(&lds[loc],     s * d.x);
                atomicAdd(&lds[loc + 1], s * d.y);
            }
        }
    }
    __syncthreads();
    float2* __restrict__ dst = (float2*)partials + (size_t)c * FB_NP_PAD + (size_t)b * FB_BSZ;
    const float2* __restrict__ src = (const float2*)lds;
    for (int k = threadIdx.x; k < FB_BSZ; k += blockDim.x) dst[k] = src[k];
}

__global__ __launch_bounds__(1024) void fb_pass2_binned(
    const int* __restrict__ nb, const float* __restrict__ areas,
    const float* __restrict__ rest, const float* __restrict__ q,
    const float2* __restrict__ dist, const float2* __restrict__ normals,
    float* __restrict__ partials, int C)
{
    __shared__ float lds[2 * FB_BSZ];
    const int b = blockIdx.x % FB_NBINS;
    const int c = blockIdx.x / FB_NBINS;
    for (int k = threadIdx.x; k < 2 * FB_BSZ; k += blockDim.x) lds[k] = 0.0f;
    __syncthreads();
    const int start = (int)((long long)c       * (N_EDGE / 4) / C) * 4;
    const int end   = (int)((long long)(c + 1) * (N_EDGE / 4) / C) * 4;
    const int4* __restrict__ nb4 = (const int4*)nb;
    for (int e = start + (int)threadIdx.x * 4; e < end; e += (int)blockDim.x * 4) {
        int4 iq = nb4[e >> 2];
        #pragma unroll
        for (int k = 0; k < 4; ++k) {
            int iv = (k == 0) ? iq.x : (k == 1) ? iq.y : (k == 2) ? iq.z : iq.w;
            if ((iv >> FB_BSZ_LOG2) == b) {
                int ee = e + k;
                int j  = nb[N_EDGE + ee];
                float2 ni = normals[iv];
                float2 nj = normals[j];
                float qq  = q[ee];
                float fc  = areas[j] * rest[j];
                float qm1 = qq - 1.0f;
                float t   = qm1 * qm1 * qm1 * qq * qq * qq;
                float kern = (qq <= 0.5f) ? fmaf(128.0f, t, 1.0f) : 64.0f * t;
                float2 d = dist[ee];
                int loc = (iv & (FB_BSZ - 1)) << 1;
                atomicAdd(&lds[loc],     -(ni.x - nj.x) + fc * kern * d.x);
                atomicAdd(&lds[loc + 1], -(ni.y - nj.y) + fc * kern * d.y);
            }
        }
    }
    __syncthreads();
    float2* __restrict__ dst = (float2*)partials + (size_t)c * FB_NP_PAD + (size_t)b * FB_BSZ;
    const float2* __restrict__ src = (const float2*)lds;
    for (int k = threadIdx.x; k < FB_BSZ; k += blockDim.x) dst[k] = src[k];
}

__global__ __launch_bounds__(256) void fb_reduce_partials(
    const float* __restrict__ partials, float* __restrict__ dst, int C)
{
    int p = blockIdx.x * blockDim.x + threadIdx.x;
    if (p >= N_PART) return;
    const float2* __restrict__ p2 = (const float2*)partials;
    float ax = 0.0f, ay = 0.0f;
    for (int c = 0; c < C; ++c) {
        float2 v = p2[(size_t)c * FB_NP_PAD + p];
        ax += v.x; ay += v.y;
    }
    ((float2*)dst)[p] = make_float2(ax, ay);
}

__global__ __launch_bounds__(256) void fb_zero2(float* __restrict__ a,
                                                float* __restrict__ b, int n) {
    int idx = blockIdx.x * blockDim.x + threadIdx.x;
    if (idx < n) { a[idx] = 0.0f; b[idx] = 0.0f; }
}

__global__ __launch_bounds__(256) void fb_pass1_atomic(
    const int* __restrict__ nb, const float* __restrict__ areas,
    const float* __restrict__ dens, const float* __restrict__ q,
    const float2* __restrict__ dist, float* __restrict__ normals)
{
    int e = blockIdx.x * blockDim.x + threadIdx.x;
    if (e >= N_EDGE) return;
    int i = nb[e];
    int j = nb[N_EDGE + e];
    float qq  = q[e];
    float fac = areas[j] / dens[j];
    const float Cw = 7.0f / (PI_F * SUPPORT * SUPPORT);
    float omq  = fmaxf(1.0f - qq, 0.0f);
    float dWdq = Cw * (-20.0f * qq * omq * omq * omq) * (1.0f / SUPPORT);
    float s = SUPPORT * fac * dWdq;
    float2 d = dist[e];
    atomicAdd(&normals[2 * i],     s * d.x);
    atomicAdd(&normals[2 * i + 1], s * d.y);
}

__global__ __launch_bounds__(256) void fb_pass2_atomic(
    const int* __restrict__ nb, const float* __restrict__ areas,
    const float* __restrict__ rest, const float* __restrict__ q,
    const float2* __restrict__ dist, const float2* __restrict__ normals,
    float* __restrict__ out)
{
    int e = blockIdx.x * blockDim.x + threadIdx.x;
    if (e >= N_EDGE) return;
    int i = nb[e];
    int j = nb[N_EDGE + e];
    float2 ni = normals[i];
    float2 nj = normals[j];
    float qq  = q[e];
    float fc  = areas[j] * rest[j];
    float qm1 = qq - 1.0f;
    float t   = qm1 * qm1 * qm1 * qq * qq * qq;
    float kern = (qq <= 0.5f) ? fmaf(128.0f, t, 1.0f) : 64.0f * t;
    float2 d = dist[e];
    atomicAdd(&out[2 * i],     -(ni.x - nj.x) + fc * kern * d.x);
    atomicAdd(&out[2 * i + 1], -(ni.y - nj.y) + fc * kern * d.y);
}

// ===========================================================================
extern "C" void kernel_launch(void* const* d_in, const int* in_sizes, int n_in,
                              void* d_out, int out_size, void* d_ws, size_t ws_size,
                              hipStream_t stream) {
    const int*   nb    = (const int*)d_in[0];     // [2*E]
    const float* areas = (const float*)d_in[1];   // [N]
    const float* dens  = (const float*)d_in[2];   // [N]
    const float* rest  = (const float*)d_in[3];   // [N]
    const float* q     = (const float*)d_in[4];   // [E]
    const float* dist  = (const float*)d_in[5];   // [E,2]
    float* out = (float*)d_out;                   // [N,2]

    // --- Sorted-path workspace layout ---
    size_t off = 0;
    auto take = [&](size_t bytes) { size_t o = off; off += (bytes + 255) & ~(size_t)255; return o; };
    size_t o_pack    = take((size_t)N_EDGE * sizeof(unsigned));
    size_t o_pay1    = take((size_t)N_EDGE * sizeof(float2));
    size_t o_pay2    = take((size_t)N_EDGE * sizeof(float2));
    size_t o_btab    = take((size_t)NCH * 16 * sizeof(unsigned));
    size_t o_normals = take((size_t)N_PART * sizeof(float2));
    size_t base_need = off;
    const size_t per_g = (size_t)(NBIN * BINSZ) * sizeof(float2);

    int G = 0;
    if (ws_size > base_need) {
        G = (int)((ws_size - base_need) / per_g);
        if (G > G_MAX) G = G_MAX;
    }

    char* ws = (char*)d_ws;

    if (G >= 6) {
        unsigned* gpack   = (unsigned*)(ws + o_pack);
        float2*   gpay1   = (float2*)(ws + o_pay1);
        float2*   gpay2   = (float2*)(ws + o_pay2);
        unsigned* btab    = (unsigned*)(ws + o_btab);
        float2*   normals = (float2*)(ws + o_normals);
        float2*   partials= (float2*)(ws + base_need);

        l1_sort<<<NCH, 1024, 0, stream>>>(
            nb, areas, dens, rest, q, (const float2*)dist,
            gpack, gpay1, gpay2, btab);
        passB<<<NBIN * G, 512, 0, stream>>>(btab, gpack, gpay1, partials, G);
        reduceG<<<(N_PART + 255) / 256, 256, 0, stream>>>(partials, normals, G);
        passD<<<NBIN * G, 512, 0, stream>>>(btab, gpack, gpay2, normals, partials, G);
        reduceG<<<(N_PART + 255) / 256, 256, 0, stream>>>(partials, (float2*)out, G);
        return;
    }

    // --- Fallback paths ---
    const size_t normals_pad = 1 << 20;
    float* normals  = (float*)d_ws;
    float* partials = (float*)((char*)d_ws + normals_pad);
    const size_t per_chunk = (size_t)FB_NP_PAD * 2 * sizeof(float);
    int C = 0;
    if (ws_size > normals_pad) {
        C = (int)((ws_size - normals_pad) / per_chunk);
        if (C > FB_C_TARGET) C = FB_C_TARGET;
    }

    if (C >= 4) {
        const int grid = FB_NBINS * C;
        fb_pass1_binned<<<grid, 1024, 0, stream>>>(
            nb, areas, dens, q, (const float2*)dist, partials, C);
        fb_reduce_partials<<<(N_PART + 255) / 256, 256, 0, stream>>>(partials, normals, C);
        fb_pass2_binned<<<grid, 1024, 0, stream>>>(
            nb, areas, rest, q, (const float2*)dist, (const float2*)normals, partials, C);
        fb_reduce_partials<<<(N_PART + 255) / 256, 256, 0, stream>>>(partials, out, C);
    } else {
        const int nv = 2 * N_PART;
        fb_zero2<<<(nv + 255) / 256, 256, 0, stream>>>(normals, out, nv);
        const int blocks = (N_EDGE + 255) / 256;
        fb_pass1_atomic<<<blocks, 256, 0, stream>>>(
            nb, areas, dens, q, (const float2*)dist, normals);
        fb_pass2_atomic<<<blocks, 256, 0, stream>>>(
            nb, areas, rest, q, (const float2*)dist, (const float2*)normals, out);
    }
}

// Round 8
// 432.072 us; speedup vs baseline: 2.3331x; 1.0436x over previous
//
#include <hip/hip_runtime.h>

// Problem constants (from reference)
constexpr int N_PART = 100000;
constexpr int N_EDGE = 6400000;
constexpr float SUPPORT = 0.05f;
constexpr float PI_F = 3.14159265358979323846f;

// ===========================================================================
// Sorted path: block-local counting sort (records staged in LDS SoA, all
// global traffic coalesced), then bin-owner LDS accumulation.
// ===========================================================================
constexpr int CH_LOG2 = 12;
constexpr int CH      = 1 << CH_LOG2;            // 4096 edges per sort chunk
constexpr int NCH     = (N_EDGE + CH - 1) / CH;  // 1563 chunks
constexpr int BIN_LOG2 = 13;
constexpr int BINSZ   = 1 << BIN_LOG2;           // 8192 particles per bin
constexpr int NBIN    = (N_PART + BINSZ - 1) / BINSZ;  // 13 bins
constexpr int G_MAX   = 39;                      // partial groups (13*39=507 blocks)
constexpr int ST_NW   = 8;                       // l1_sort waves (512 threads)

// --- Level 1: per-chunk counting sort + payload precompute.
// LDS ~65 KB -> 2 blocks/CU; SoA records -> bank-uniform scatter.
// Output (per chunk, bin-grouped): pack = (i_loc13 << 17) | j17,
// pay1 = s*d, pay2 = fc*kern*d.  btab[t*16+b] = segment start; [13] = len.
__global__ __launch_bounds__(512) void l1_sort(
    const int* __restrict__ nb,        // [2*E]
    const float* __restrict__ areas,   // [N]
    const float* __restrict__ dens,    // [N]
    const float* __restrict__ rest,    // [N]
    const float* __restrict__ q,       // [E]
    const float2* __restrict__ dist,   // [E]
    unsigned* __restrict__ gpack,
    float2* __restrict__ gpay1,
    float2* __restrict__ gpay2,
    unsigned* __restrict__ btab)       // [NCH*16] u32
{
    __shared__ unsigned rec_pack[CH];         // 16 KB each, SoA: bank-uniform
    __shared__ float    rec_q[CH];
    __shared__ float    rec_dx[CH];
    __shared__ float    rec_dy[CH];
    __shared__ unsigned hist[ST_NW * NBIN];
    __shared__ unsigned curw[ST_NW * NBIN];
    __shared__ unsigned base[NBIN + 1];

    const int t   = blockIdx.x;
    const int c0  = t * CH;
    const int len = min(CH, N_EDGE - c0);
    const int tid = threadIdx.x;
    const int wid = tid >> 6;                 // 8 waves

    for (int k = tid; k < ST_NW * NBIN; k += 512) hist[k] = 0u;
    __syncthreads();

    // Phase 1: coalesced read of i, per-wave histogram
    for (int idx = tid; idx < len; idx += 512) {
        unsigned i = (unsigned)nb[c0 + idx];
        atomicAdd(&hist[wid * NBIN + (i >> BIN_LOG2)], 1u);
    }
    __syncthreads();

    // Serial scan: bin bases + per-(wave,bin) cursors (13*8 = 104 iters)
    if (tid == 0) {
        unsigned run = 0;
        for (int b = 0; b < NBIN; ++b) {
            base[b] = run;
            for (int w = 0; w < ST_NW; ++w) {
                curw[w * NBIN + b] = run;
                run += hist[w * NBIN + b];
            }
        }
        base[NBIN] = run;   // == len
    }
    __syncthreads();
    if (tid < NBIN)  btab[t * 16 + tid]  = base[tid];
    if (tid == NBIN) btab[t * 16 + NBIN] = (unsigned)len;

    // Phase 2: coalesced read of edge data; rank via own wave's cursor;
    // scatter SoA record into LDS (4x ds_write_b32, bank-uniform).
    for (int idx = tid; idx < len; idx += 512) {
        unsigned i = (unsigned)nb[c0 + idx];
        unsigned j = (unsigned)nb[N_EDGE + c0 + idx];
        float   qq = q[c0 + idx];
        float2  d  = dist[c0 + idx];
        unsigned bin = i >> BIN_LOG2;
        unsigned r = atomicAdd(&curw[wid * NBIN + bin], 1u) & (CH - 1);
        rec_pack[r] = ((i & (BINSZ - 1)) << 17) | j;
        rec_q[r]    = qq;
        rec_dx[r]   = d.x;
        rec_dy[r]   = d.y;
    }
    __syncthreads();

    // Phase 3: walk sorted positions (LDS reads coalesced); gather only the
    // L2-resident areas/dens/rest; write everything coalesced.
    const float Cw = 7.0f / (PI_F * SUPPORT * SUPPORT);
    for (int p = tid; p < len; p += 512) {
        unsigned pack = rec_pack[p];
        float qq = rec_q[p];
        float dx = rec_dx[p], dy = rec_dy[p];
        unsigned j = pack & 0x1FFFFu;

        // pass-1 payload: SUPPORT * (areas[j]/dens[j]) * dWdq(q)
        float omq  = fmaxf(1.0f - qq, 0.0f);
        float dWdq = Cw * (-20.0f * qq * omq * omq * omq) * (1.0f / SUPPORT);
        float s    = SUPPORT * (areas[j] / dens[j]) * dWdq;

        // cohesion payload: areas[j]*rest[j]*kern(q)  (net sign +, see R1)
        float qm1  = qq - 1.0f;
        float tt   = qm1 * qm1 * qm1 * qq * qq * qq;
        float kern = (qq <= 0.5f) ? fmaf(128.0f, tt, 1.0f) : 64.0f * tt;
        float fc   = areas[j] * rest[j] * kern;

        int o = c0 + p;
        gpack[o] = pack;
        gpay1[o] = make_float2(s * dx, s * dy);
        gpay2[o] = make_float2(fc * dx, fc * dy);
    }
}

// --- Pass B: accumulate normals per bin; split x/y accumulators (bank-
// uniform atomics); per-wave chunk walking.
__global__ __launch_bounds__(512) void passB(
    const unsigned* __restrict__ btab,
    const unsigned* __restrict__ gpack,
    const float2* __restrict__ gpay1,
    float2* __restrict__ partials,       // [G][NBIN*BINSZ]
    int G)
{
    __shared__ float accx[BINSZ];        // 32 KB
    __shared__ float accy[BINSZ];        // 32 KB
    const int b = blockIdx.x % NBIN;
    const int g = blockIdx.x / NBIN;
    const int wave = threadIdx.x >> 6;
    const int lane = threadIdx.x & 63;

    for (int k = threadIdx.x; k < BINSZ; k += 512) { accx[k] = 0.0f; accy[k] = 0.0f; }
    __syncthreads();

    const int t0 = (int)((long long)g * NCH / G);
    const int t1 = (int)((long long)(g + 1) * NCH / G);
    for (int t = t0 + wave; t < t1; t += 8) {
        const int c0  = t * CH;
        const unsigned ln = min(btab[t * 16 + NBIN], (unsigned)CH);
        unsigned sb = min(btab[t * 16 + b], ln);
        unsigned se = min(btab[t * 16 + b + 1], ln);
        for (unsigned k = sb + lane; k < se; k += 64) {
            int o = c0 + (int)k;
            unsigned pk = gpack[o];
            float2 p = gpay1[o];
            unsigned loc = (pk >> 17) & (BINSZ - 1);   // LDS-safe
            atomicAdd(&accx[loc], p.x);
            atomicAdd(&accy[loc], p.y);
        }
    }
    __syncthreads();

    float2* __restrict__ dst = partials + (size_t)g * (NBIN * BINSZ) + (size_t)b * BINSZ;
    for (int k = threadIdx.x; k < BINSZ; k += 512)
        dst[k] = make_float2(accx[k], accy[k]);
}

// --- Pass D: acc_i += (n_j - n_i + coh) per edge --------------------------
__global__ __launch_bounds__(512) void passD(
    const unsigned* __restrict__ btab,
    const unsigned* __restrict__ gpack,
    const float2* __restrict__ gpay2,
    const float2* __restrict__ normals,  // [N]
    float2* __restrict__ partials,
    int G)
{
    __shared__ float accx[BINSZ];
    __shared__ float accy[BINSZ];
    const int b = blockIdx.x % NBIN;
    const int g = blockIdx.x / NBIN;
    const int wave = threadIdx.x >> 6;
    const int lane = threadIdx.x & 63;

    for (int k = threadIdx.x; k < BINSZ; k += 512) { accx[k] = 0.0f; accy[k] = 0.0f; }
    __syncthreads();

    const int gbase = b * BINSZ;
    const int t0 = (int)((long long)g * NCH / G);
    const int t1 = (int)((long long)(g + 1) * NCH / G);
    for (int t = t0 + wave; t < t1; t += 8) {
        const int c0  = t * CH;
        const unsigned ln = min(btab[t * 16 + NBIN], (unsigned)CH);
        unsigned sb = min(btab[t * 16 + b], ln);
        unsigned se = min(btab[t * 16 + b + 1], ln);
        for (unsigned k = sb + lane; k < se; k += 64) {
            int o = c0 + (int)k;
            unsigned pk = gpack[o];
            float2 coh = gpay2[o];
            unsigned loc = (pk >> 17) & (BINSZ - 1);            // LDS-safe
            unsigned j   = min(pk & 0x1FFFFu, (unsigned)(N_PART - 1));
            unsigned ii  = min((unsigned)(gbase + loc), (unsigned)(N_PART - 1));
            float2 nj = normals[j];            // random, L2-resident 800 KB
            float2 ni = normals[ii];           // hot 64 KB window
            atomicAdd(&accx[loc], nj.x - ni.x + coh.x);
            atomicAdd(&accy[loc], nj.y - ni.y + coh.y);
        }
    }
    __syncthreads();

    float2* __restrict__ dst = partials + (size_t)g * (NBIN * BINSZ) + (size_t)b * BINSZ;
    for (int k = threadIdx.x; k < BINSZ; k += 512)
        dst[k] = make_float2(accx[k], accy[k]);
}

// dst[p] = sum_g partials[g][p]
__global__ __launch_bounds__(256) void reduceG(
    const float2* __restrict__ partials, float2* __restrict__ dst, int G)
{
    int p = blockIdx.x * blockDim.x + threadIdx.x;
    if (p >= N_PART) return;
    float ax = 0.0f, ay = 0.0f;
    for (int g = 0; g < G; ++g) {
        float2 v = partials[(size_t)g * (NBIN * BINSZ) + p];
        ax += v.x; ay += v.y;
    }
    dst[p] = make_float2(ax, ay);
}

// ===========================================================================
// Fallback 1 (R3, proven 631 us): binned multi-read path. Fallback 2: atomics.
// ===========================================================================
constexpr int FB_BSZ_LOG2 = 13;
constexpr int FB_BSZ   = 1 << FB_BSZ_LOG2;
constexpr int FB_NBINS = (N_PART + FB_BSZ - 1) / FB_BSZ;
constexpr int FB_NP_PAD = FB_NBINS * FB_BSZ;
constexpr int FB_C_TARGET = 39;

__global__ __launch_bounds__(1024) void fb_pass1_binned(
    const int* __restrict__ nb, const float* __restrict__ areas,
    const float* __restrict__ dens, const float* __restrict__ q,
    const float2* __restrict__ dist, float* __restrict__ partials, int C)
{
    __shared__ float lds[2 * FB_BSZ];
    const int b = blockIdx.x % FB_NBINS;
    const int c = blockIdx.x / FB_NBINS;
    for (int k = threadIdx.x; k < 2 * FB_BSZ; k += blockDim.x) lds[k] = 0.0f;
    __syncthreads();
    const int start = (int)((long long)c       * (N_EDGE / 4) / C) * 4;
    const int end   = (int)((long long)(c + 1) * (N_EDGE / 4) / C) * 4;
    const int4* __restrict__ nb4 = (const int4*)nb;
    const float Cw = 7.0f / (PI_F * SUPPORT * SUPPORT);
    for (int e = start + (int)threadIdx.x * 4; e < end; e += (int)blockDim.x * 4) {
        int4 iq = nb4[e >> 2];
        #pragma unroll
        for (int k = 0; k < 4; ++k) {
            int iv = (k == 0) ? iq.x : (k == 1) ? iq.y : (k == 2) ? iq.z : iq.w;
            if ((iv >> FB_BSZ_LOG2) == b) {
                int ee = e + k;
                int j  = nb[N_EDGE + ee];
                float qq  = q[ee];
                float fac = areas[j] / dens[j];
                float omq  = fmaxf(1.0f - qq, 0.0f);
                float dWdq = Cw * (-20.0f * qq * omq * omq * omq) * (1.0f / SUPPORT);
                float s = SUPPORT * fac * dWdq;
                float2 d = dist[ee];
                int loc = (iv & (FB_BSZ - 1)) << 1;
                atomicAdd(&lds[loc],     s * d.x);
                atomicAdd(&lds[loc + 1], s * d.y);
            }
        }
    }
    __syncthreads();
    float2* __restrict__ dst = (float2*)partials + (size_t)c * FB_NP_PAD + (size_t)b * FB_BSZ;
    const float2* __restrict__ src = (const float2*)lds;
    for (int k = threadIdx.x; k < FB_BSZ; k += blockDim.x) dst[k] = src[k];
}

__global__ __launch_bounds__(1024) void fb_pass2_binned(
    const int* __restrict__ nb, const float* __restrict__ areas,
    const float* __restrict__ rest, const float* __restrict__ q,
    const float2* __restrict__ dist, const float2* __restrict__ normals,
    float* __restrict__ partials, int C)
{
    __shared__ float lds[2 * FB_BSZ];
    const int b = blockIdx.x % FB_NBINS;
    const int c = blockIdx.x / FB_NBINS;
    for (int k = threadIdx.x; k < 2 * FB_BSZ; k += blockDim.x) lds[k] = 0.0f;
    __syncthreads();
    const int start = (int)((long long)c       * (N_EDGE / 4) / C) * 4;
    const int end   = (int)((long long)(c + 1) * (N_EDGE / 4) / C) * 4;
    const int4* __restrict__ nb4 = (const int4*)nb;
    for (int e = start + (int)threadIdx.x * 4; e < end; e += (int)blockDim.x * 4) {
        int4 iq = nb4[e >> 2];
        #pragma unroll
        for (int k = 0; k < 4; ++k) {
            int iv = (k == 0) ? iq.x : (k == 1) ? iq.y : (k == 2) ? iq.z : iq.w;
            if ((iv >> FB_BSZ_LOG2) == b) {
                int ee = e + k;
                int j  = nb[N_EDGE + ee];
                float2 ni = normals[iv];
                float2 nj = normals[j];
                float qq  = q[ee];
                float fc  = areas[j] * rest[j];
                float qm1 = qq - 1.0f;
                float t   = qm1 * qm1 * qm1 * qq * qq * qq;
                float kern = (qq <= 0.5f) ? fmaf(128.0f, t, 1.0f) : 64.0f * t;
                float2 d = dist[ee];
                int loc = (iv & (FB_BSZ - 1)) << 1;
                atomicAdd(&lds[loc],     -(ni.x - nj.x) + fc * kern * d.x);
                atomicAdd(&lds[loc + 1], -(ni.y - nj.y) + fc * kern * d.y);
            }
        }
    }
    __syncthreads();
    float2* __restrict__ dst = (float2*)partials + (size_t)c * FB_NP_PAD + (size_t)b * FB_BSZ;
    const float2* __restrict__ src = (const float2*)lds;
    for (int k = threadIdx.x; k < FB_BSZ; k += blockDim.x) dst[k] = src[k];
}

__global__ __launch_bounds__(256) void fb_reduce_partials(
    const float* __restrict__ partials, float* __restrict__ dst, int C)
{
    int p = blockIdx.x * blockDim.x + threadIdx.x;
    if (p >= N_PART) return;
    const float2* __restrict__ p2 = (const float2*)partials;
    float ax = 0.0f, ay = 0.0f;
    for (int c = 0; c < C; ++c) {
        float2 v = p2[(size_t)c * FB_NP_PAD + p];
        ax += v.x; ay += v.y;
    }
    ((float2*)dst)[p] = make_float2(ax, ay);
}

__global__ __launch_bounds__(256) void fb_zero2(float* __restrict__ a,
                                                float* __restrict__ b, int n) {
    int idx = blockIdx.x * blockDim.x + threadIdx.x;
    if (idx < n) { a[idx] = 0.0f; b[idx] = 0.0f; }
}

__global__ __launch_bounds__(256) void fb_pass1_atomic(
    const int* __restrict__ nb, const float* __restrict__ areas,
    const float* __restrict__ dens, const float* __restrict__ q,
    const float2* __restrict__ dist, float* __restrict__ normals)
{
    int e = blockIdx.x * blockDim.x + threadIdx.x;
    if (e >= N_EDGE) return;
    int i = nb[e];
    int j = nb[N_EDGE + e];
    float qq  = q[e];
    float fac = areas[j] / dens[j];
    const float Cw = 7.0f / (PI_F * SUPPORT * SUPPORT);
    float omq  = fmaxf(1.0f - qq, 0.0f);
    float dWdq = Cw * (-20.0f * qq * omq * omq * omq) * (1.0f / SUPPORT);
    float s = SUPPORT * fac * dWdq;
    float2 d = dist[e];
    atomicAdd(&normals[2 * i],     s * d.x);
    atomicAdd(&normals[2 * i + 1], s * d.y);
}

__global__ __launch_bounds__(256) void fb_pass2_atomic(
    const int* __restrict__ nb, const float* __restrict__ areas,
    const float* __restrict__ rest, const float* __restrict__ q,
    const float2* __restrict__ dist, const float2* __restrict__ normals,
    float* __restrict__ out)
{
    int e = blockIdx.x * blockDim.x + threadIdx.x;
    if (e >= N_EDGE) return;
    int i = nb[e];
    int j = nb[N_EDGE + e];
    float2 ni = normals[i];
    float2 nj = normals[j];
    float qq  = q[e];
    float fc  = areas[j] * rest[j];
    float qm1 = qq - 1.0f;
    float t   = qm1 * qm1 * qm1 * qq * qq * qq;
    float kern = (qq <= 0.5f) ? fmaf(128.0f, t, 1.0f) : 64.0f * t;
    float2 d = dist[e];
    atomicAdd(&out[2 * i],     -(ni.x - nj.x) + fc * kern * d.x);
    atomicAdd(&out[2 * i + 1], -(ni.y - nj.y) + fc * kern * d.y);
}

// ===========================================================================
extern "C" void kernel_launch(void* const* d_in, const int* in_sizes, int n_in,
                              void* d_out, int out_size, void* d_ws, size_t ws_size,
                              hipStream_t stream) {
    const int*   nb    = (const int*)d_in[0];     // [2*E]
    const float* areas = (const float*)d_in[1];   // [N]
    const float* dens  = (const float*)d_in[2];   // [N]
    const float* rest  = (const float*)d_in[3];   // [N]
    const float* q     = (const float*)d_in[4];   // [E]
    const float* dist  = (const float*)d_in[5];   // [E,2]
    float* out = (float*)d_out;                   // [N,2]

    // --- Sorted-path workspace layout ---
    size_t off = 0;
    auto take = [&](size_t bytes) { size_t o = off; off += (bytes + 255) & ~(size_t)255; return o; };
    size_t o_pack    = take((size_t)N_EDGE * sizeof(unsigned));
    size_t o_pay1    = take((size_t)N_EDGE * sizeof(float2));
    size_t o_pay2    = take((size_t)N_EDGE * sizeof(float2));
    size_t o_btab    = take((size_t)NCH * 16 * sizeof(unsigned));
    size_t o_normals = take((size_t)N_PART * sizeof(float2));
    size_t base_need = off;
    const size_t per_g = (size_t)(NBIN * BINSZ) * sizeof(float2);

    int G = 0;
    if (ws_size > base_need) {
        G = (int)((ws_size - base_need) / per_g);
        if (G > G_MAX) G = G_MAX;
    }

    char* ws = (char*)d_ws;

    if (G >= 6) {
        unsigned* gpack   = (unsigned*)(ws + o_pack);
        float2*   gpay1   = (float2*)(ws + o_pay1);
        float2*   gpay2   = (float2*)(ws + o_pay2);
        unsigned* btab    = (unsigned*)(ws + o_btab);
        float2*   normals = (float2*)(ws + o_normals);
        float2*   partials= (float2*)(ws + base_need);

        l1_sort<<<NCH, 512, 0, stream>>>(
            nb, areas, dens, rest, q, (const float2*)dist,
            gpack, gpay1, gpay2, btab);
        passB<<<NBIN * G, 512, 0, stream>>>(btab, gpack, gpay1, partials, G);
        reduceG<<<(N_PART + 255) / 256, 256, 0, stream>>>(partials, normals, G);
        passD<<<NBIN * G, 512, 0, stream>>>(btab, gpack, gpay2, normals, partials, G);
        reduceG<<<(N_PART + 255) / 256, 256, 0, stream>>>(partials, (float2*)out, G);
        return;
    }

    // --- Fallback paths ---
    const size_t normals_pad = 1 << 20;
    float* normals  = (float*)d_ws;
    float* partials = (float*)((char*)d_ws + normals_pad);
    const size_t per_chunk = (size_t)FB_NP_PAD * 2 * sizeof(float);
    int C = 0;
    if (ws_size > normals_pad) {
        C = (int)((ws_size - normals_pad) / per_chunk);
        if (C > FB_C_TARGET) C = FB_C_TARGET;
    }

    if (C >= 4) {
        const int grid = FB_NBINS * C;
        fb_pass1_binned<<<grid, 1024, 0, stream>>>(
            nb, areas, dens, q, (const float2*)dist, partials, C);
        fb_reduce_partials<<<(N_PART + 255) / 256, 256, 0, stream>>>(partials, normals, C);
        fb_pass2_binned<<<grid, 1024, 0, stream>>>(
            nb, areas, rest, q, (const float2*)dist, (const float2*)normals, partials, C);
        fb_reduce_partials<<<(N_PART + 255) / 256, 256, 0, stream>>>(partials, out, C);
    } else {
        const int nv = 2 * N_PART;
        fb_zero2<<<(nv + 255) / 256, 256, 0, stream>>>(normals, out, nv);
        const int blocks = (N_EDGE + 255) / 256;
        fb_pass1_atomic<<<blocks, 256, 0, stream>>>(
            nb, areas, dens, q, (const float2*)dist, normals);
        fb_pass2_atomic<<<blocks, 256, 0, stream>>>(
            nb, areas, rest, q, (const float2*)dist, (const float2*)normals, out);
    }
}